// Round 12
// baseline (80.116 us; speedup 1.0000x reference)
//
#include <hip/hip_runtime.h>
#include <hip/hip_bf16.h>
#include <math.h>

typedef short bf16x8 __attribute__((ext_vector_type(8)));
typedef float f32x4 __attribute__((ext_vector_type(4)));
typedef float f32x16 __attribute__((ext_vector_type(16)));
typedef unsigned int u32;
typedef unsigned int u32x4 __attribute__((ext_vector_type(4)));
typedef unsigned short u16;

constexpr int Bb = 8, LQn = 1024, LKn = 1024, En = 512, Hn = 8, Dn = 64;
constexpr int Mtok = Bb * LQn;  // 8192
// 1/sqrt(512) * log2(e): folded into K so softmax is a bare exp2
constexpr float KCOEF = 0.06376246332977306f;

__device__ __forceinline__ u16 f2bf(float f) {
  u32 u = __builtin_bit_cast(u32, f);
  u32 r = (u + 0x7fffu + ((u >> 16) & 1u)) >> 16;
  return (u16)r;
}
__device__ __forceinline__ float bf2f(u16 h) {
  u32 u = ((u32)h) << 16;
  return __builtin_bit_cast(float, u);
}
__device__ __forceinline__ u16 f2bf_hw(float f) {
  return __builtin_bit_cast(u16, __float2bfloat16(f));  // RNE
}

// async 16B global -> LDS copy (wave-uniform LDS base + lane*16 required)
__device__ __forceinline__ void async_lds16(const void* gsrc, void* ldst) {
  __builtin_amdgcn_global_load_lds(
      (const __attribute__((address_space(1))) u32*)gsrc,
      (__attribute__((address_space(3))) u32*)ldst, 16, 0, 0);
}

// ------------- unified prep: fp32->bf16 for x1/x2 (+sin-masks) and Wq/Wk/Wv -------------
// kbias is written PRE-BAKED as the score bias: 0.0 (keep) or -3e38 (masked).
__global__ void prep_kernel(const float* __restrict__ x1, const float* __restrict__ x2,
                            u16* __restrict__ x1b, u16* __restrict__ x2b,
                            float* __restrict__ qmask, float* __restrict__ kbias,
                            const float* __restrict__ Wq, const float* __restrict__ Wk,
                            const float* __restrict__ Wv, u16* __restrict__ wqb,
                            u16* __restrict__ wkb, u16* __restrict__ wvb) {
  int blk = blockIdx.x;
  if (blk < 4096) {
    int id = blk * 4 + (threadIdx.x >> 6);
    int lane = threadIdx.x & 63;
    const float* x; u16* xb; int row; bool isq;
    if (id < Mtok) { x = x1; xb = x1b; row = id; isq = true; }
    else           { x = x2; xb = x2b; row = id - Mtok; isq = false; }
    const float4* p = reinterpret_cast<const float4*>(x + (size_t)row * En);
    ushort4* ob = reinterpret_cast<ushort4*>(xb + (size_t)row * En);
    double s = 0.0;
#pragma unroll
    for (int j = 0; j < En / 256; ++j) {
      float4 v = p[lane + j * 64];
      s += (double)v.x + (double)v.y + (double)v.z + (double)v.w;
      ushort4 o;
      o.x = f2bf(v.x); o.y = f2bf(v.y); o.z = f2bf(v.z); o.w = f2bf(v.w);
      ob[lane + j * 64] = o;
    }
#pragma unroll
    for (int off = 32; off > 0; off >>= 1) s += __shfl_down(s, off, 64);
    if (lane == 0) {
      float sv = (float)sin(fabs(s));
      if (isq) qmask[row] = sv;
      else     kbias[row] = sv > 0.f ? 0.f : -3.0e38f;
    }
  } else {
    int n4 = En * En / 4;  // 65536
    int j = (blk - 4096) * 256 + threadIdx.x;
    const float* src; u16* dst;
    if (j < n4) { src = Wq; dst = wqb; }
    else if (j < 2 * n4) { src = Wk; dst = wkb; j -= n4; }
    else { src = Wv; dst = wvb; j -= 2 * n4; }
    float4 v = reinterpret_cast<const float4*>(src)[j];
    ushort4 o;
    o.x = f2bf(v.x); o.y = f2bf(v.y); o.z = f2bf(v.z); o.w = f2bf(v.w);
    reinterpret_cast<ushort4*>(dst)[j] = o;
  }
}

// ---------------- GEMM core: C = coef*relu(A*Bm^T + bias), 128x128 tile, 512 thr ----
template <int BIAS_ROW>
__device__ __forceinline__ void gemm_core(
    const u16* __restrict__ A, const u16* __restrict__ Bm,
    const float* __restrict__ bias, u16* __restrict__ C,
    int ldc, float coef, int row0, int col0) {
  constexpr int K = 512, BK = 64;
  __shared__ u16 sA[2][128 * BK];
  __shared__ u16 sB[2][128 * BK];
  int tid = threadIdx.x;
  int lane = tid & 63;
  int w = tid >> 6;
  int wm = w >> 2, wn = w & 3;
  int rgrp = lane >> 4, cidx = lane & 15;

  f32x4 acc[4][2];
#pragma unroll
  for (int mi = 0; mi < 4; ++mi)
#pragma unroll
    for (int ni = 0; ni < 2; ++ni) acc[mi][ni] = f32x4{0.f, 0.f, 0.f, 0.f};

  auto stage = [&](int kt, int buf) {
    int k0 = kt * BK;
#pragma unroll
    for (int rr = 0; rr < 2; ++rr) {  // A tile: 128x64 bf16 = 1024 16B chunks
      int cid = rr * 512 + tid;
      int r = cid >> 3, c = cid & 7;
      int cg = c ^ (r & 7);
      async_lds16(A + (size_t)(row0 + r) * K + k0 + cg * 8, &sA[buf][cid * 8]);
    }
#pragma unroll
    for (int rr = 0; rr < 2; ++rr) {  // B tile: 128x64
      int cid = rr * 512 + tid;
      int r = cid >> 3, c = cid & 7;
      int cg = c ^ (r & 7);
      async_lds16(Bm + (size_t)(col0 + r) * K + k0 + cg * 8, &sB[buf][cid * 8]);
    }
  };

  stage(0, 0);
  __syncthreads();  // drains stage(0)

  for (int kt = 0; kt < K / BK; ++kt) {
    int cur = kt & 1;
    if (kt < K / BK - 1) stage(kt + 1, cur ^ 1);  // issue next-tile loads first
#pragma unroll
    for (int kk = 0; kk < 2; ++kk) {
      bf16x8 a[4], b[2];
#pragma unroll
      for (int mi = 0; mi < 4; ++mi) {
        int row = wm * 64 + mi * 16 + cidx;
        a[mi] = *reinterpret_cast<const bf16x8*>(
            &sA[cur][row * BK + ((kk * 4 + rgrp) ^ (row & 7)) * 8]);
      }
#pragma unroll
      for (int ni = 0; ni < 2; ++ni) {
        int row = wn * 32 + ni * 16 + cidx;
        b[ni] = *reinterpret_cast<const bf16x8*>(
            &sB[cur][row * BK + ((kk * 4 + rgrp) ^ (row & 7)) * 8]);
      }
#pragma unroll
      for (int mi = 0; mi < 4; ++mi)
#pragma unroll
        for (int ni = 0; ni < 2; ++ni)
          acc[mi][ni] = __builtin_amdgcn_mfma_f32_16x16x32_bf16(a[mi], b[ni], acc[mi][ni], 0, 0, 0);
    }
    __syncthreads();  // implicit vmcnt(0) drain lands AFTER compute
  }
  // epilogue: bias + relu + coef + bf16 store. C/D layout: col=lane&15, row=(lane>>4)*4+r
#pragma unroll
  for (int mi = 0; mi < 4; ++mi)
#pragma unroll
    for (int ni = 0; ni < 2; ++ni)
#pragma unroll
      for (int r = 0; r < 4; ++r) {
        int grow = row0 + wm * 64 + mi * 16 + rgrp * 4 + r;
        int gcol = col0 + wn * 32 + ni * 16 + cidx;
        float v = acc[mi][ni][r] + (BIAS_ROW ? bias[grow] : bias[gcol]);
        v = v > 0.f ? v : 0.f;
        C[(size_t)grow * ldc + gcol] = f2bf(v * coef);
      }
}

// All three projections in one launch: z=0 Q, z=1 K (pre-scaled), z=2 V^T
__global__ __launch_bounds__(512, 4) void gemm3(
    const u16* __restrict__ x1b, const u16* __restrict__ wqb, const float* __restrict__ bq,
    u16* __restrict__ qbq,
    const u16* __restrict__ x2b, const u16* __restrict__ wkb, const float* __restrict__ bk,
    u16* __restrict__ kbk,
    const u16* __restrict__ wvb, const float* __restrict__ bv, u16* __restrict__ vtb) {
  int z = blockIdx.z;
  if (z == 0) {
    gemm_core<0>(x1b, wqb, bq, qbq, En, 1.0f, blockIdx.x * 128, blockIdx.y * 128);
  } else if (z == 1) {
    gemm_core<0>(x2b, wkb, bk, kbk, En, KCOEF, blockIdx.x * 128, blockIdx.y * 128);
  } else {
    // V^T = relu(Wv * x2b^T + bv): rows = feature (bias per row), cols = token
    gemm_core<1>(wvb, x2b, bv, vtb, Mtok, 1.0f, blockIdx.y * 128, blockIdx.x * 128);
  }
}

// ---------------- fused masked attention: 32x32x16 MFMA, in-register P ----------------
// grid: (B*H, LQ/64); 4 waves = (q-half x k-half); dbuf K/V (32KB) + Q tile (8KB).
// QK^T as S^T = mfma(K,Q): D q-col = lane&31 matches PV A-row layout -> P never
// touches LDS: RNE bf16 pack + v_permlane32_swap redistribute k across lane halves.
// BUGFIX vs R10/R11: PV's V-fragment chunk must include the wave's k-half offset
// (kh*4) — without it both k-halves read V columns 0..31 (deterministic ~0.047 err).
// Wave (qh, kh=1) partial O/den folded into (qh, kh=0) via one LDS exchange at end.
__global__ __launch_bounds__(256, 4) void attn_kernel(
    const u16* __restrict__ qb, const u16* __restrict__ kb, const u16* __restrict__ vtb,
    const float* __restrict__ kbias, const float* __restrict__ qmask,
    float* __restrict__ out) {
  __shared__ u16 sK[2][64 * 64];
  __shared__ u16 sV[2][64 * 64];    // V^T tile: rows=d (64), cols=k (64)
  __shared__ u16 sQP[64 * 64];      // Q tile; reused as f32 O-exchange slab at end
  int tid = threadIdx.x, lane = tid & 63, w = tid >> 6;
  int bh = blockIdx.x, qblk = blockIdx.y;
  int b = bh >> 3, h = bh & 7;
  int l31 = lane & 31, hi = lane >> 5;
  int qh = w & 1, kh = w >> 1;  // wave = (q-half, k-half)

  const u16* qbase = qb + ((size_t)(b * LQn) + qblk * 64) * En + h * Dn;
  const u16* kbase = kb + (size_t)(b * LKn) * En + h * Dn;
  const u16* vbase = vtb + (size_t)(h * Dn) * Mtok + b * LKn;
  const float* kmb = kbias + b * LKn;

  auto stageKV = [&](int kt, int buf) {
#pragma unroll
    for (int rr = 0; rr < 2; ++rr) {
      int cid = rr * 256 + tid;
      int r = cid >> 3, c = cid & 7;
      int cg = c ^ (r & 7);
      async_lds16(kbase + (size_t)(kt * 64 + r) * En + cg * 8, &sK[buf][cid * 8]);
      async_lds16(vbase + (size_t)r * Mtok + kt * 64 + cg * 8, &sV[buf][cid * 8]);
    }
  };

#pragma unroll
  for (int rr = 0; rr < 2; ++rr) {  // Q tile 64x64 into sQP
    int cid = rr * 256 + tid;
    int r = cid >> 3, c = cid & 7;
    int cg = c ^ (r & 7);
    async_lds16(qbase + (size_t)r * En + cg * 8, &sQP[cid * 8]);
  }
  stageKV(0, 0);
  __syncthreads();

  // Q B-frags (32x32x16: col=lane&31=q, contr d=(lane>>5)*8+e), chain over d=64
  bf16x8 qf[4];
  {
    int qrow = qh * 32 + l31;
#pragma unroll
    for (int c = 0; c < 4; ++c) {
      int chunk = (c * 2 + hi) ^ (qrow & 7);
      qf[c] = *reinterpret_cast<const bf16x8*>(&sQP[qrow * 64 + chunk * 8]);
    }
  }

  f32x16 acc[2];  // O partial [32q x 64d]: 2 d-tiles x 16 regs
  acc[0] = 0.f; acc[1] = 0.f;
  float den = 0.f;  // per-lane: q = l31 (this wave's k-half only)

  for (int kt = 0; kt < LKn / 64; ++kt) {
    int cur = kt & 1;
    if (kt < LKn / 64 - 1) stageKV(kt + 1, cur ^ 1);  // prefetch before compute
    // --- QK^T: S^T[32k x 32q] = K(A) x Q(B), 4 chained over d ---
    bf16x8 kf[4];
    int krow = kh * 32 + l31;
    const u16* sKc = sK[cur];
#pragma unroll
    for (int c = 0; c < 4; ++c) {
      int chunk = (c * 2 + hi) ^ (krow & 7);
      kf[c] = *reinterpret_cast<const bf16x8*>(&sKc[krow * 64 + chunk * 8]);
    }
    f32x16 s;
#pragma unroll
    for (int j = 0; j < 4; ++j) {  // C-init = kbias at k=(reg&3)+8*(reg>>2)+4*hi
      float4 kb4 = *reinterpret_cast<const float4*>(&kmb[kt * 64 + kh * 32 + 8 * j + 4 * hi]);
      s[4 * j + 0] = kb4.x; s[4 * j + 1] = kb4.y;
      s[4 * j + 2] = kb4.z; s[4 * j + 3] = kb4.w;
    }
#pragma unroll
    for (int c = 0; c < 4; ++c)
      s = __builtin_amdgcn_mfma_f32_32x32x16_bf16(kf[c], qf[c], s, 0, 0, 0);
    // --- softmax: P = exp2(S); RNE-pack to bf16; den from ROUNDED values ---
    u32 pw[8];
#pragma unroll
    for (int m = 0; m < 8; ++m) {
      float p0 = __builtin_amdgcn_exp2f(s[2 * m]);
      float p1 = __builtin_amdgcn_exp2f(s[2 * m + 1]);
      u16 b0 = f2bf_hw(p0), b1 = f2bf_hw(p1);
      den += bf2f(b0) + bf2f(b1);  // numerator/denominator share rounding
      pw[m] = (u32)b0 | ((u32)b1 << 16);
    }
    // --- redistribute to PV A-frag layout (k=hi*8+e) via permlane32_swap ---
    bf16x8 paf[2];
#pragma unroll
    for (int kc = 0; kc < 2; ++kc) {
      u32 a0 = pw[4 * kc + 0], a2 = pw[4 * kc + 2];
      u32 a1 = pw[4 * kc + 1], a3 = pw[4 * kc + 3];
      asm volatile("v_permlane32_swap_b32 %0, %1" : "+v"(a0), "+v"(a2));
      asm volatile("v_permlane32_swap_b32 %0, %1" : "+v"(a1), "+v"(a3));
      u32x4 t; t[0] = a0; t[1] = a1; t[2] = a2; t[3] = a3;
      paf[kc] = __builtin_bit_cast(bf16x8, t);
    }
    // --- PV: O[32q x 64d] += P(A) x V(B), per d-tile chain over wave's 32k ---
    __builtin_amdgcn_s_setprio(1);  // T5
    const u16* sVc = sV[cur];
#pragma unroll
    for (int dt = 0; dt < 2; ++dt) {
      int vrow = dt * 32 + l31;
#pragma unroll
      for (int kc = 0; kc < 2; ++kc) {
        int chunk = (kh * 4 + kc * 2 + hi) ^ (vrow & 7);  // kh*4: this wave's k-half
        bf16x8 vf = *reinterpret_cast<const bf16x8*>(&sVc[vrow * 64 + chunk * 8]);
        acc[dt] = __builtin_amdgcn_mfma_f32_32x32x16_bf16(paf[kc], vf, acc[dt], 0, 0, 0);
      }
    }
    __builtin_amdgcn_s_setprio(0);
    __syncthreads();  // drain (covers next-tile prefetch) after full compute phase
  }
  // den: fold hi halves -> lane holds den_half[q=l31] over this wave's k-half
  den += __shfl_xor(den, 32, 64);

  // cross-wave (k-half) reduction: kh=1 waves dump O/den to LDS, kh=0 finalize.
  float* dslab = (float*)sV;  // staging done; reuse
  if (kh == 1) {
    float* aslab = (w == 2) ? (float*)sQP : (float*)sK;
#pragma unroll
    for (int dt = 0; dt < 2; ++dt)
#pragma unroll
      for (int rg = 0; rg < 16; ++rg)
        aslab[(dt * 16 + rg) * 64 + lane] = acc[dt][rg];
    if (lane < 32) dslab[qh * 32 + l31] = den;
  }
  __syncthreads();
  if (kh == 0) {
    float* pslab = (w == 0) ? (float*)sQP : (float*)sK;
    float denf = den + dslab[qh * 32 + l31];
    if (lane < 32) dslab[64 + qh * 32 + l31] = denf;
    const float* qmb = qmask + (size_t)b * LQn + qblk * 64 + qh * 32;
    const u16* qres = qbase + (size_t)(qh * 32) * En;
    float* obase = out + ((size_t)(b * LQn) + qblk * 64 + qh * 32) * En + h * Dn;
#pragma unroll
    for (int dt = 0; dt < 2; ++dt)
#pragma unroll
      for (int rg = 0; rg < 16; ++rg) {
        int q = (rg & 3) + 8 * (rg >> 2) + 4 * hi;
        float a = acc[dt][rg] + pslab[(dt * 16 + rg) * 64 + lane];
        float denq = dslab[64 + qh * 32 + q];
        float fac = qmb[q] / denq;
        int d = dt * 32 + l31;
        float v = a * fac + bf2f(qres[(size_t)q * En + d]);
        obase[(size_t)q * En + d] = v;
      }
  }
}

extern "C" void kernel_launch(void* const* d_in, const int* in_sizes, int n_in,
                              void* d_out, int out_size, void* d_ws, size_t ws_size,
                              hipStream_t stream) {
  const float* x1 = (const float*)d_in[0];
  const float* x2 = (const float*)d_in[1];
  const float* Wq = (const float*)d_in[2];
  const float* bq = (const float*)d_in[3];
  const float* Wk = (const float*)d_in[4];
  const float* bk = (const float*)d_in[5];
  const float* Wv = (const float*)d_in[6];
  const float* bv = (const float*)d_in[7];
  float* out = (float*)d_out;

  char* ws = (char*)d_ws;
  size_t o = 0;
  u16* x1b = (u16*)(ws + o); o += (size_t)Mtok * En * 2;
  u16* x2b = (u16*)(ws + o); o += (size_t)Mtok * En * 2;
  u16* wqb = (u16*)(ws + o); o += (size_t)En * En * 2;
  u16* wkb = (u16*)(ws + o); o += (size_t)En * En * 2;
  u16* wvb = (u16*)(ws + o); o += (size_t)En * En * 2;
  u16* qbq = (u16*)(ws + o); o += (size_t)Mtok * En * 2;
  u16* kbk = (u16*)(ws + o); o += (size_t)Mtok * En * 2;
  u16* vtb = (u16*)(ws + o); o += (size_t)Mtok * En * 2;  // [E][Mtok] transposed
  float* kbias = (float*)(ws + o); o += (size_t)Mtok * 4;
  float* qmask = (float*)(ws + o); o += (size_t)Mtok * 4;

  // prep: 4096 mask/cvt blocks + 768 weight-cvt blocks
  prep_kernel<<<4864, 256, 0, stream>>>(x1, x2, x1b, x2b, qmask, kbias,
                                        Wq, Wk, Wv, wqb, wkb, wvb);

  dim3 g3(Mtok / 128, En / 128, 3);  // (64, 4, 3)
  gemm3<<<g3, 512, 0, stream>>>(x1b, wqb, bq, qbq, x2b, wkb, bk, kbk, wvb, bv, vtb);

  dim3 ga(Bb * Hn, LQn / 64);  // (64, 16)
  attn_kernel<<<ga, 256, 0, stream>>>(qbq, kbk, vtb, kbias, qmask, out);
}

// Round 13
// 71.486 us; speedup vs baseline: 1.1207x; 1.1207x over previous
//
#include <hip/hip_runtime.h>
#include <hip/hip_bf16.h>
#include <math.h>

typedef short bf16x8 __attribute__((ext_vector_type(8)));
typedef float f32x4 __attribute__((ext_vector_type(4)));
typedef unsigned int u32;
typedef unsigned short u16;

constexpr int Bb = 8, LQn = 1024, LKn = 1024, En = 512, Hn = 8, Dn = 64;
constexpr int Mtok = Bb * LQn;  // 8192
// 1/sqrt(512) * log2(e): folded into K so softmax is a bare exp2
constexpr float KCOEF = 0.06376246332977306f;

__device__ __forceinline__ u16 f2bf(float f) {
  u32 u = __builtin_bit_cast(u32, f);
  u32 r = (u + 0x7fffu + ((u >> 16) & 1u)) >> 16;
  return (u16)r;
}
__device__ __forceinline__ float bf2f(u16 h) {
  u32 u = ((u32)h) << 16;
  return __builtin_bit_cast(float, u);
}
__device__ __forceinline__ u16 f2bf_hw(float f) {
  return __builtin_bit_cast(u16, __float2bfloat16(f));  // RNE, same as f2bf
}

// async 16B global -> LDS copy (wave-uniform LDS base + lane*16 required)
__device__ __forceinline__ void async_lds16(const void* gsrc, void* ldst) {
  __builtin_amdgcn_global_load_lds(
      (const __attribute__((address_space(1))) u32*)gsrc,
      (__attribute__((address_space(3))) u32*)ldst, 16, 0, 0);
}

// ------------- unified prep: fp32->bf16 for x1/x2 (+sin-masks) and Wq/Wk/Wv -------------
// kbias is written PRE-BAKED as the score bias: 0.0 (keep) or -3e38 (masked).
__global__ void prep_kernel(const float* __restrict__ x1, const float* __restrict__ x2,
                            u16* __restrict__ x1b, u16* __restrict__ x2b,
                            float* __restrict__ qmask, float* __restrict__ kbias,
                            const float* __restrict__ Wq, const float* __restrict__ Wk,
                            const float* __restrict__ Wv, u16* __restrict__ wqb,
                            u16* __restrict__ wkb, u16* __restrict__ wvb) {
  int blk = blockIdx.x;
  if (blk < 4096) {
    int id = blk * 4 + (threadIdx.x >> 6);
    int lane = threadIdx.x & 63;
    const float* x; u16* xb; int row; bool isq;
    if (id < Mtok) { x = x1; xb = x1b; row = id; isq = true; }
    else           { x = x2; xb = x2b; row = id - Mtok; isq = false; }
    const float4* p = reinterpret_cast<const float4*>(x + (size_t)row * En);
    ushort4* ob = reinterpret_cast<ushort4*>(xb + (size_t)row * En);
    double s = 0.0;
#pragma unroll
    for (int j = 0; j < En / 256; ++j) {
      float4 v = p[lane + j * 64];
      s += (double)v.x + (double)v.y + (double)v.z + (double)v.w;
      ushort4 o;
      o.x = f2bf(v.x); o.y = f2bf(v.y); o.z = f2bf(v.z); o.w = f2bf(v.w);
      ob[lane + j * 64] = o;
    }
#pragma unroll
    for (int off = 32; off > 0; off >>= 1) s += __shfl_down(s, off, 64);
    if (lane == 0) {
      float sv = (float)sin(fabs(s));
      if (isq) qmask[row] = sv;
      else     kbias[row] = sv > 0.f ? 0.f : -3.0e38f;
    }
  } else {
    int n4 = En * En / 4;  // 65536
    int j = (blk - 4096) * 256 + threadIdx.x;
    const float* src; u16* dst;
    if (j < n4) { src = Wq; dst = wqb; }
    else if (j < 2 * n4) { src = Wk; dst = wkb; j -= n4; }
    else { src = Wv; dst = wvb; j -= 2 * n4; }
    float4 v = reinterpret_cast<const float4*>(src)[j];
    ushort4 o;
    o.x = f2bf(v.x); o.y = f2bf(v.y); o.z = f2bf(v.z); o.w = f2bf(v.w);
    reinterpret_cast<ushort4*>(dst)[j] = o;
  }
}

// ---------------- GEMM core: C = coef*relu(A*Bm^T + bias), 128x128 tile, 512 thr ----
template <int BIAS_ROW>
__device__ __forceinline__ void gemm_core(
    const u16* __restrict__ A, const u16* __restrict__ Bm,
    const float* __restrict__ bias, u16* __restrict__ C,
    int ldc, float coef, int row0, int col0) {
  constexpr int K = 512, BK = 64;
  __shared__ u16 sA[2][128 * BK];
  __shared__ u16 sB[2][128 * BK];
  int tid = threadIdx.x;
  int lane = tid & 63;
  int w = tid >> 6;
  int wm = w >> 2, wn = w & 3;
  int rgrp = lane >> 4, cidx = lane & 15;

  f32x4 acc[4][2];
#pragma unroll
  for (int mi = 0; mi < 4; ++mi)
#pragma unroll
    for (int ni = 0; ni < 2; ++ni) acc[mi][ni] = f32x4{0.f, 0.f, 0.f, 0.f};

  auto stage = [&](int kt, int buf) {
    int k0 = kt * BK;
#pragma unroll
    for (int rr = 0; rr < 2; ++rr) {  // A tile: 128x64 bf16 = 1024 16B chunks
      int cid = rr * 512 + tid;
      int r = cid >> 3, c = cid & 7;
      int cg = c ^ (r & 7);
      async_lds16(A + (size_t)(row0 + r) * K + k0 + cg * 8, &sA[buf][cid * 8]);
    }
#pragma unroll
    for (int rr = 0; rr < 2; ++rr) {  // B tile: 128x64
      int cid = rr * 512 + tid;
      int r = cid >> 3, c = cid & 7;
      int cg = c ^ (r & 7);
      async_lds16(Bm + (size_t)(col0 + r) * K + k0 + cg * 8, &sB[buf][cid * 8]);
    }
  };

  stage(0, 0);
  __syncthreads();  // drains stage(0)

  for (int kt = 0; kt < K / BK; ++kt) {
    int cur = kt & 1;
    if (kt < K / BK - 1) stage(kt + 1, cur ^ 1);  // issue next-tile loads first
#pragma unroll
    for (int kk = 0; kk < 2; ++kk) {
      bf16x8 a[4], b[2];
#pragma unroll
      for (int mi = 0; mi < 4; ++mi) {
        int row = wm * 64 + mi * 16 + cidx;
        a[mi] = *reinterpret_cast<const bf16x8*>(
            &sA[cur][row * BK + ((kk * 4 + rgrp) ^ (row & 7)) * 8]);
      }
#pragma unroll
      for (int ni = 0; ni < 2; ++ni) {
        int row = wn * 32 + ni * 16 + cidx;
        b[ni] = *reinterpret_cast<const bf16x8*>(
            &sB[cur][row * BK + ((kk * 4 + rgrp) ^ (row & 7)) * 8]);
      }
#pragma unroll
      for (int mi = 0; mi < 4; ++mi)
#pragma unroll
        for (int ni = 0; ni < 2; ++ni)
          acc[mi][ni] = __builtin_amdgcn_mfma_f32_16x16x32_bf16(a[mi], b[ni], acc[mi][ni], 0, 0, 0);
    }
    __syncthreads();  // implicit vmcnt(0) drain lands AFTER compute
  }
  // epilogue: bias + relu + coef + bf16 store. C/D layout: col=lane&15, row=(lane>>4)*4+r
#pragma unroll
  for (int mi = 0; mi < 4; ++mi)
#pragma unroll
    for (int ni = 0; ni < 2; ++ni)
#pragma unroll
      for (int r = 0; r < 4; ++r) {
        int grow = row0 + wm * 64 + mi * 16 + rgrp * 4 + r;
        int gcol = col0 + wn * 32 + ni * 16 + cidx;
        float v = acc[mi][ni][r] + (BIAS_ROW ? bias[grow] : bias[gcol]);
        v = v > 0.f ? v : 0.f;
        C[(size_t)grow * ldc + gcol] = f2bf_hw(v * coef);
      }
}

// All three projections in one launch: z=0 Q, z=1 K (pre-scaled), z=2 V^T
__global__ __launch_bounds__(512, 4) void gemm3(
    const u16* __restrict__ x1b, const u16* __restrict__ wqb, const float* __restrict__ bq,
    u16* __restrict__ qbq,
    const u16* __restrict__ x2b, const u16* __restrict__ wkb, const float* __restrict__ bk,
    u16* __restrict__ kbk,
    const u16* __restrict__ wvb, const float* __restrict__ bv, u16* __restrict__ vtb) {
  int z = blockIdx.z;
  if (z == 0) {
    gemm_core<0>(x1b, wqb, bq, qbq, En, 1.0f, blockIdx.x * 128, blockIdx.y * 128);
  } else if (z == 1) {
    gemm_core<0>(x2b, wkb, bk, kbk, En, KCOEF, blockIdx.x * 128, blockIdx.y * 128);
  } else {
    // V^T = relu(Wv * x2b^T + bv): rows = feature (bias per row), cols = token
    gemm_core<1>(wvb, x2b, bv, vtb, Mtok, 1.0f, blockIdx.y * 128, blockIdx.x * 128);
  }
}

// ---------------- fused masked attention (R9 structure — best measured) ----------------
// grid: (B*H, LQ/64); 4 waves x 16 q-rows; dbuf K/V; unioned Q/P LDS (40KB, 4 blk/CU).
// S^T = mfma(K, Q): lane holds 4 consecutive k -> packed ds_write_b64 P^T slice.
// kbias pre-baked (0/-3e38) loads straight into the MFMA C-init.
__global__ __launch_bounds__(256, 4) void attn_kernel(
    const u16* __restrict__ qb, const u16* __restrict__ kb, const u16* __restrict__ vtb,
    const float* __restrict__ kbias, const float* __restrict__ qmask,
    float* __restrict__ out) {
  __shared__ u16 sK[2][64 * 64];
  __shared__ u16 sV[2][64 * 64];    // V^T tile: rows=d (64), cols=k (64)
  __shared__ u16 sQP[64 * 64];      // Q tile, then wave-private P^T 16x64 slices
  int tid = threadIdx.x, lane = tid & 63, w = tid >> 6;
  int bh = blockIdx.x, qblk = blockIdx.y;
  int b = bh >> 3, h = bh & 7;
  int rgrp = lane >> 4, cidx = lane & 15;

  const u16* qbase = qb + ((size_t)(b * LQn) + qblk * 64) * En + h * Dn;
  const u16* kbase = kb + (size_t)(b * LKn) * En + h * Dn;
  const u16* vbase = vtb + (size_t)(h * Dn) * Mtok + b * LKn;
  const float* kmb = kbias + b * LKn;

  auto stageKV = [&](int kt, int buf) {
#pragma unroll
    for (int rr = 0; rr < 2; ++rr) {
      int cid = rr * 256 + tid;
      int r = cid >> 3, c = cid & 7;
      int cg = c ^ (r & 7);
      async_lds16(kbase + (size_t)(kt * 64 + r) * En + cg * 8, &sK[buf][cid * 8]);
      async_lds16(vbase + (size_t)r * Mtok + kt * 64 + cg * 8, &sV[buf][cid * 8]);
    }
  };

#pragma unroll
  for (int rr = 0; rr < 2; ++rr) {  // Q tile 64x64 into sQP
    int cid = rr * 256 + tid;
    int r = cid >> 3, c = cid & 7;
    int cg = c ^ (r & 7);
    async_lds16(qbase + (size_t)r * En + cg * 8, &sQP[cid * 8]);
  }
  stageKV(0, 0);
  __syncthreads();

  bf16x8 qa0, qa1;
  {
    int row = w * 16 + cidx;
    qa0 = *reinterpret_cast<const bf16x8*>(&sQP[row * 64 + (rgrp ^ (row & 7)) * 8]);
    qa1 = *reinterpret_cast<const bf16x8*>(&sQP[row * 64 + ((4 + rgrp) ^ (row & 7)) * 8]);
  }

  f32x4 acc_o[4];
#pragma unroll
  for (int dt = 0; dt < 4; ++dt) acc_o[dt] = f32x4{0.f, 0.f, 0.f, 0.f};
  float den = 0.f;  // per-lane: q=cidx, k in {kt*64 + ktile*16 + rgrp*4 + r}

  int prow = w * 16 + cidx;
  char* sPbyte = reinterpret_cast<char*>(sQP);

  for (int kt = 0; kt < LKn / 64; ++kt) {
    int cur = kt & 1;
    if (kt < LKn / 64 - 1) stageKV(kt + 1, cur ^ 1);  // prefetch before compute
    // S^T = K Q^T (per-wave 64k x 16q), P = exp2(S + kbias) -> packed P^T LDS
#pragma unroll
    for (int ktile = 0; ktile < 4; ++ktile) {
      int krow = ktile * 16 + cidx;
      bf16x8 kf0 = *reinterpret_cast<const bf16x8*>(
          &sK[cur][krow * 64 + (rgrp ^ (krow & 7)) * 8]);
      bf16x8 kf1 = *reinterpret_cast<const bf16x8*>(
          &sK[cur][krow * 64 + ((4 + rgrp) ^ (krow & 7)) * 8]);
      float4 km4 = *reinterpret_cast<const float4*>(&kmb[kt * 64 + ktile * 16 + rgrp * 4]);
      f32x4 s;
      s[0] = km4.x; s[1] = km4.y; s[2] = km4.z; s[3] = km4.w;  // pre-baked bias
      // swapped operands: D[k_row, q_col]; K/Q fragment bytes identical to unswapped
      __builtin_amdgcn_s_setprio(1);  // T5 on QK cluster too
      s = __builtin_amdgcn_mfma_f32_16x16x32_bf16(kf0, qa0, s, 0, 0, 0);
      s = __builtin_amdgcn_mfma_f32_16x16x32_bf16(kf1, qa1, s, 0, 0, 0);
      __builtin_amdgcn_s_setprio(0);
      float p0 = __builtin_amdgcn_exp2f(s[0]);
      float p1 = __builtin_amdgcn_exp2f(s[1]);
      float p2 = __builtin_amdgcn_exp2f(s[2]);
      float p3 = __builtin_amdgcn_exp2f(s[3]);
      den += (p0 + p1) + (p2 + p3);
      ushort4 pk;
      pk.x = f2bf_hw(p0); pk.y = f2bf_hw(p1); pk.z = f2bf_hw(p2); pk.w = f2bf_hw(p3);
      // P^T[q=prow][k=ktile*16+rgrp*4 .. +3]: granule=ktile*2+(rgrp>>1), half=rgrp&1
      int gran = ktile * 2 + (rgrp >> 1);
      int boff = prow * 128 + ((gran ^ (prow & 7)) << 4) + ((rgrp & 1) << 3);
      *reinterpret_cast<ushort4*>(sPbyte + boff) = pk;
    }
    // PV: out(16q x 64d) += P(16q x 64k) * V(64k x 64d); wave-private P, no barrier
    __builtin_amdgcn_s_setprio(1);  // T5: favor MFMA-entering wave
#pragma unroll
    for (int kk = 0; kk < 2; ++kk) {
      bf16x8 pa = *reinterpret_cast<const bf16x8*>(
          &sQP[prow * 64 + ((kk * 4 + rgrp) ^ (prow & 7)) * 8]);
#pragma unroll
      for (int dt = 0; dt < 4; ++dt) {
        int vrow = dt * 16 + cidx;
        bf16x8 vf = *reinterpret_cast<const bf16x8*>(
            &sV[cur][vrow * 64 + ((kk * 4 + rgrp) ^ (vrow & 7)) * 8]);
        acc_o[dt] = __builtin_amdgcn_mfma_f32_16x16x32_bf16(pa, vf, acc_o[dt], 0, 0, 0);
      }
    }
    __builtin_amdgcn_s_setprio(0);
    __syncthreads();  // drain (covers next-tile prefetch) after full compute phase
  }
  // full denominator for q=cidx: sum across the 4 rgrp groups
  den += __shfl_xor(den, 16, 64);
  den += __shfl_xor(den, 32, 64);

  const float* qmb = qmask + (size_t)b * LQn + qblk * 64 + w * 16;
  const u16* qres = qbase + (size_t)(w * 16) * En;
  float* obase = out + ((size_t)(b * LQn) + qblk * 64 + w * 16) * En + h * Dn;
#pragma unroll
  for (int r = 0; r < 4; ++r) {
    int qr = rgrp * 4 + r;
    float denq = __shfl(den, qr, 64);  // lane qr holds full den for q=qr
    float fac = qmb[qr] / denq;
#pragma unroll
    for (int dt = 0; dt < 4; ++dt) {
      float v = acc_o[dt][r] * fac + bf2f(qres[(size_t)qr * En + dt * 16 + cidx]);
      obase[(size_t)qr * En + dt * 16 + cidx] = v;
    }
  }
}

extern "C" void kernel_launch(void* const* d_in, const int* in_sizes, int n_in,
                              void* d_out, int out_size, void* d_ws, size_t ws_size,
                              hipStream_t stream) {
  const float* x1 = (const float*)d_in[0];
  const float* x2 = (const float*)d_in[1];
  const float* Wq = (const float*)d_in[2];
  const float* bq = (const float*)d_in[3];
  const float* Wk = (const float*)d_in[4];
  const float* bk = (const float*)d_in[5];
  const float* Wv = (const float*)d_in[6];
  const float* bv = (const float*)d_in[7];
  float* out = (float*)d_out;

  char* ws = (char*)d_ws;
  size_t o = 0;
  u16* x1b = (u16*)(ws + o); o += (size_t)Mtok * En * 2;
  u16* x2b = (u16*)(ws + o); o += (size_t)Mtok * En * 2;
  u16* wqb = (u16*)(ws + o); o += (size_t)En * En * 2;
  u16* wkb = (u16*)(ws + o); o += (size_t)En * En * 2;
  u16* wvb = (u16*)(ws + o); o += (size_t)En * En * 2;
  u16* qbq = (u16*)(ws + o); o += (size_t)Mtok * En * 2;
  u16* kbk = (u16*)(ws + o); o += (size_t)Mtok * En * 2;
  u16* vtb = (u16*)(ws + o); o += (size_t)Mtok * En * 2;  // [E][Mtok] transposed
  float* kbias = (float*)(ws + o); o += (size_t)Mtok * 4;
  float* qmask = (float*)(ws + o); o += (size_t)Mtok * 4;

  // prep: 4096 mask/cvt blocks + 768 weight-cvt blocks
  prep_kernel<<<4864, 256, 0, stream>>>(x1, x2, x1b, x2b, qmask, kbias,
                                        Wq, Wk, Wv, wqb, wkb, wvb);

  dim3 g3(Mtok / 128, En / 128, 3);  // (64, 4, 3)
  gemm3<<<g3, 512, 0, stream>>>(x1b, wqb, bq, qbq, x2b, wkb, bk, kbk, wvb, bv, vtb);

  dim3 ga(Bb * Hn, LQn / 64);  // (64, 16)
  attn_kernel<<<ga, 256, 0, stream>>>(qbq, kbk, vtb, kbias, qmask, out);
}

// Round 14
// 64.961 us; speedup vs baseline: 1.2333x; 1.1004x over previous
//
#include <hip/hip_runtime.h>
#include <hip/hip_bf16.h>
#include <math.h>

typedef short bf16x8 __attribute__((ext_vector_type(8)));
typedef float f32x4 __attribute__((ext_vector_type(4)));
typedef unsigned int u32;
typedef unsigned short u16;

constexpr int Bb = 8, LQn = 1024, LKn = 1024, En = 512, Hn = 8, Dn = 64;
constexpr int Mtok = Bb * LQn;  // 8192
// 1/sqrt(512) * log2(e): folded into K so softmax is a bare exp2
constexpr float KCOEF = 0.06376246332977306f;

__device__ __forceinline__ u16 f2bf(float f) {
  u32 u = __builtin_bit_cast(u32, f);
  u32 r = (u + 0x7fffu + ((u >> 16) & 1u)) >> 16;
  return (u16)r;
}
__device__ __forceinline__ float bf2f(u16 h) {
  u32 u = ((u32)h) << 16;
  return __builtin_bit_cast(float, u);
}
__device__ __forceinline__ u16 f2bf_hw(float f) {
  return __builtin_bit_cast(u16, __float2bfloat16(f));  // RNE
}

// async 16B global -> LDS copy (wave-uniform LDS base + lane*16 required)
__device__ __forceinline__ void async_lds16(const void* gsrc, void* ldst) {
  __builtin_amdgcn_global_load_lds(
      (const __attribute__((address_space(1))) u32*)gsrc,
      (__attribute__((address_space(3))) u32*)ldst, 16, 0, 0);
}

// ------------- unified prep: fp32->bf16 for x1/x2 (+sin-masks) and Wq/Wk/Wv -------------
// kbias is written PRE-BAKED as the score bias: 0.0 (keep) or -3e38 (masked).
__global__ void prep_kernel(const float* __restrict__ x1, const float* __restrict__ x2,
                            u16* __restrict__ x1b, u16* __restrict__ x2b,
                            float* __restrict__ qmask, float* __restrict__ kbias,
                            const float* __restrict__ Wq, const float* __restrict__ Wk,
                            const float* __restrict__ Wv, u16* __restrict__ wqb,
                            u16* __restrict__ wkb, u16* __restrict__ wvb) {
  int blk = blockIdx.x;
  if (blk < 4096) {
    int id = blk * 4 + (threadIdx.x >> 6);
    int lane = threadIdx.x & 63;
    const float* x; u16* xb; int row; bool isq;
    if (id < Mtok) { x = x1; xb = x1b; row = id; isq = true; }
    else           { x = x2; xb = x2b; row = id - Mtok; isq = false; }
    const float4* p = reinterpret_cast<const float4*>(x + (size_t)row * En);
    ushort4* ob = reinterpret_cast<ushort4*>(xb + (size_t)row * En);
    double s = 0.0;
#pragma unroll
    for (int j = 0; j < En / 256; ++j) {
      float4 v = p[lane + j * 64];
      s += (double)v.x + (double)v.y + (double)v.z + (double)v.w;
      ushort4 o;
      o.x = f2bf(v.x); o.y = f2bf(v.y); o.z = f2bf(v.z); o.w = f2bf(v.w);
      ob[lane + j * 64] = o;
    }
#pragma unroll
    for (int off = 32; off > 0; off >>= 1) s += __shfl_down(s, off, 64);
    if (lane == 0) {
      float sv = (float)sin(fabs(s));
      if (isq) qmask[row] = sv;
      else     kbias[row] = sv > 0.f ? 0.f : -3.0e38f;
    }
  } else {
    int n4 = En * En / 4;  // 65536
    int j = (blk - 4096) * 256 + threadIdx.x;
    const float* src; u16* dst;
    if (j < n4) { src = Wq; dst = wqb; }
    else if (j < 2 * n4) { src = Wk; dst = wkb; j -= n4; }
    else { src = Wv; dst = wvb; j -= 2 * n4; }
    float4 v = reinterpret_cast<const float4*>(src)[j];
    ushort4 o;
    o.x = f2bf(v.x); o.y = f2bf(v.y); o.z = f2bf(v.z); o.w = f2bf(v.w);
    reinterpret_cast<ushort4*>(dst)[j] = o;
  }
}

// ------- GEMM core: C = coef*relu(A*Bm^T + bias), 128x128 tile, 512 thr --------
// SINGLE-buffered 32KB LDS -> 3 blocks/CU (launch_bounds(512,6), VGPR<=85):
// grid 768 = exactly one residency round (vs dbuf 64KB: 2 blk/CU, 1.5 rounds).
// Co-resident sibling blocks cover the stage->compute serialization (m114).
template <int BIAS_ROW>
__device__ __forceinline__ void gemm_core(
    const u16* __restrict__ A, const u16* __restrict__ Bm,
    const float* __restrict__ bias, u16* __restrict__ C,
    int ldc, float coef, int row0, int col0) {
  constexpr int K = 512, BK = 64;
  __shared__ u16 sA[128 * BK];
  __shared__ u16 sB[128 * BK];
  int tid = threadIdx.x;
  int lane = tid & 63;
  int w = tid >> 6;
  int wm = w >> 2, wn = w & 3;
  int rgrp = lane >> 4, cidx = lane & 15;

  f32x4 acc[4][2];
#pragma unroll
  for (int mi = 0; mi < 4; ++mi)
#pragma unroll
    for (int ni = 0; ni < 2; ++ni) acc[mi][ni] = f32x4{0.f, 0.f, 0.f, 0.f};

  for (int kt = 0; kt < K / BK; ++kt) {
    int k0 = kt * BK;
    __syncthreads();  // previous compute done before overwrite
#pragma unroll
    for (int rr = 0; rr < 2; ++rr) {  // A tile: 128x64 bf16 = 1024 16B chunks
      int cid = rr * 512 + tid;
      int r = cid >> 3, c = cid & 7;
      int cg = c ^ (r & 7);
      async_lds16(A + (size_t)(row0 + r) * K + k0 + cg * 8, &sA[cid * 8]);
    }
#pragma unroll
    for (int rr = 0; rr < 2; ++rr) {  // B tile: 128x64
      int cid = rr * 512 + tid;
      int r = cid >> 3, c = cid & 7;
      int cg = c ^ (r & 7);
      async_lds16(Bm + (size_t)(col0 + r) * K + k0 + cg * 8, &sB[cid * 8]);
    }
    __syncthreads();  // drain stage (implicit vmcnt(0))
#pragma unroll
    for (int kk = 0; kk < 2; ++kk) {
      bf16x8 a[4], b[2];
#pragma unroll
      for (int mi = 0; mi < 4; ++mi) {
        int row = wm * 64 + mi * 16 + cidx;
        a[mi] = *reinterpret_cast<const bf16x8*>(
            &sA[row * BK + ((kk * 4 + rgrp) ^ (row & 7)) * 8]);
      }
#pragma unroll
      for (int ni = 0; ni < 2; ++ni) {
        int row = wn * 32 + ni * 16 + cidx;
        b[ni] = *reinterpret_cast<const bf16x8*>(
            &sB[row * BK + ((kk * 4 + rgrp) ^ (row & 7)) * 8]);
      }
#pragma unroll
      for (int mi = 0; mi < 4; ++mi)
#pragma unroll
        for (int ni = 0; ni < 2; ++ni)
          acc[mi][ni] = __builtin_amdgcn_mfma_f32_16x16x32_bf16(a[mi], b[ni], acc[mi][ni], 0, 0, 0);
    }
  }
  // epilogue: bias + relu + coef + bf16 store. C/D layout: col=lane&15, row=(lane>>4)*4+r
#pragma unroll
  for (int mi = 0; mi < 4; ++mi)
#pragma unroll
    for (int ni = 0; ni < 2; ++ni)
#pragma unroll
      for (int r = 0; r < 4; ++r) {
        int grow = row0 + wm * 64 + mi * 16 + rgrp * 4 + r;
        int gcol = col0 + wn * 32 + ni * 16 + cidx;
        float v = acc[mi][ni][r] + (BIAS_ROW ? bias[grow] : bias[gcol]);
        v = v > 0.f ? v : 0.f;
        C[(size_t)grow * ldc + gcol] = f2bf_hw(v * coef);
      }
}

// All three projections in one launch: z=0 Q, z=1 K (pre-scaled), z=2 V^T
__global__ __launch_bounds__(512, 6) void gemm3(
    const u16* __restrict__ x1b, const u16* __restrict__ wqb, const float* __restrict__ bq,
    u16* __restrict__ qbq,
    const u16* __restrict__ x2b, const u16* __restrict__ wkb, const float* __restrict__ bk,
    u16* __restrict__ kbk,
    const u16* __restrict__ wvb, const float* __restrict__ bv, u16* __restrict__ vtb) {
  int z = blockIdx.z;
  if (z == 0) {
    gemm_core<0>(x1b, wqb, bq, qbq, En, 1.0f, blockIdx.x * 128, blockIdx.y * 128);
  } else if (z == 1) {
    gemm_core<0>(x2b, wkb, bk, kbk, En, KCOEF, blockIdx.x * 128, blockIdx.y * 128);
  } else {
    // V^T = relu(Wv * x2b^T + bv): rows = feature (bias per row), cols = token
    gemm_core<1>(wvb, x2b, bv, vtb, Mtok, 1.0f, blockIdx.y * 128, blockIdx.x * 128);
  }
}

// ---------------- fused masked attention (R9 structure — best measured) ----------------
// grid: (B*H, LQ/64); 4 waves x 16 q-rows; dbuf K/V; unioned Q/P LDS (40KB, 4 blk/CU).
// S^T = mfma(K, Q): lane holds 4 consecutive k -> packed ds_write_b64 P^T slice.
// kbias pre-baked (0/-3e38) loads straight into the MFMA C-init. T5 on PV only.
__global__ __launch_bounds__(256, 4) void attn_kernel(
    const u16* __restrict__ qb, const u16* __restrict__ kb, const u16* __restrict__ vtb,
    const float* __restrict__ kbias, const float* __restrict__ qmask,
    float* __restrict__ out) {
  __shared__ u16 sK[2][64 * 64];
  __shared__ u16 sV[2][64 * 64];    // V^T tile: rows=d (64), cols=k (64)
  __shared__ u16 sQP[64 * 64];      // Q tile, then wave-private P^T 16x64 slices
  int tid = threadIdx.x, lane = tid & 63, w = tid >> 6;
  int bh = blockIdx.x, qblk = blockIdx.y;
  int b = bh >> 3, h = bh & 7;
  int rgrp = lane >> 4, cidx = lane & 15;

  const u16* qbase = qb + ((size_t)(b * LQn) + qblk * 64) * En + h * Dn;
  const u16* kbase = kb + (size_t)(b * LKn) * En + h * Dn;
  const u16* vbase = vtb + (size_t)(h * Dn) * Mtok + b * LKn;
  const float* kmb = kbias + b * LKn;

  auto stageKV = [&](int kt, int buf) {
#pragma unroll
    for (int rr = 0; rr < 2; ++rr) {
      int cid = rr * 256 + tid;
      int r = cid >> 3, c = cid & 7;
      int cg = c ^ (r & 7);
      async_lds16(kbase + (size_t)(kt * 64 + r) * En + cg * 8, &sK[buf][cid * 8]);
      async_lds16(vbase + (size_t)r * Mtok + kt * 64 + cg * 8, &sV[buf][cid * 8]);
    }
  };

#pragma unroll
  for (int rr = 0; rr < 2; ++rr) {  // Q tile 64x64 into sQP
    int cid = rr * 256 + tid;
    int r = cid >> 3, c = cid & 7;
    int cg = c ^ (r & 7);
    async_lds16(qbase + (size_t)r * En + cg * 8, &sQP[cid * 8]);
  }
  stageKV(0, 0);
  __syncthreads();

  bf16x8 qa0, qa1;
  {
    int row = w * 16 + cidx;
    qa0 = *reinterpret_cast<const bf16x8*>(&sQP[row * 64 + (rgrp ^ (row & 7)) * 8]);
    qa1 = *reinterpret_cast<const bf16x8*>(&sQP[row * 64 + ((4 + rgrp) ^ (row & 7)) * 8]);
  }

  f32x4 acc_o[4];
#pragma unroll
  for (int dt = 0; dt < 4; ++dt) acc_o[dt] = f32x4{0.f, 0.f, 0.f, 0.f};
  float den = 0.f;  // per-lane: q=cidx, k in {kt*64 + ktile*16 + rgrp*4 + r}

  int prow = w * 16 + cidx;
  char* sPbyte = reinterpret_cast<char*>(sQP);

  for (int kt = 0; kt < LKn / 64; ++kt) {
    int cur = kt & 1;
    if (kt < LKn / 64 - 1) stageKV(kt + 1, cur ^ 1);  // prefetch before compute
    // S^T = K Q^T (per-wave 64k x 16q), P = exp2(S + kbias) -> packed P^T LDS
#pragma unroll
    for (int ktile = 0; ktile < 4; ++ktile) {
      int krow = ktile * 16 + cidx;
      bf16x8 kf0 = *reinterpret_cast<const bf16x8*>(
          &sK[cur][krow * 64 + (rgrp ^ (krow & 7)) * 8]);
      bf16x8 kf1 = *reinterpret_cast<const bf16x8*>(
          &sK[cur][krow * 64 + ((4 + rgrp) ^ (krow & 7)) * 8]);
      float4 km4 = *reinterpret_cast<const float4*>(&kmb[kt * 64 + ktile * 16 + rgrp * 4]);
      f32x4 s;
      s[0] = km4.x; s[1] = km4.y; s[2] = km4.z; s[3] = km4.w;  // pre-baked bias
      // swapped operands: D[k_row, q_col]; K/Q fragment bytes identical to unswapped
      s = __builtin_amdgcn_mfma_f32_16x16x32_bf16(kf0, qa0, s, 0, 0, 0);
      s = __builtin_amdgcn_mfma_f32_16x16x32_bf16(kf1, qa1, s, 0, 0, 0);
      float p0 = __builtin_amdgcn_exp2f(s[0]);
      float p1 = __builtin_amdgcn_exp2f(s[1]);
      float p2 = __builtin_amdgcn_exp2f(s[2]);
      float p3 = __builtin_amdgcn_exp2f(s[3]);
      den += (p0 + p1) + (p2 + p3);
      ushort4 pk;
      pk.x = f2bf_hw(p0); pk.y = f2bf_hw(p1); pk.z = f2bf_hw(p2); pk.w = f2bf_hw(p3);
      // P^T[q=prow][k=ktile*16+rgrp*4 .. +3]: granule=ktile*2+(rgrp>>1), half=rgrp&1
      int gran = ktile * 2 + (rgrp >> 1);
      int boff = prow * 128 + ((gran ^ (prow & 7)) << 4) + ((rgrp & 1) << 3);
      *reinterpret_cast<ushort4*>(sPbyte + boff) = pk;
    }
    // PV: out(16q x 64d) += P(16q x 64k) * V(64k x 64d); wave-private P, no barrier
    __builtin_amdgcn_s_setprio(1);  // T5: favor MFMA-entering wave
#pragma unroll
    for (int kk = 0; kk < 2; ++kk) {
      bf16x8 pa = *reinterpret_cast<const bf16x8*>(
          &sQP[prow * 64 + ((kk * 4 + rgrp) ^ (prow & 7)) * 8]);
#pragma unroll
      for (int dt = 0; dt < 4; ++dt) {
        int vrow = dt * 16 + cidx;
        bf16x8 vf = *reinterpret_cast<const bf16x8*>(
            &sV[cur][vrow * 64 + ((kk * 4 + rgrp) ^ (vrow & 7)) * 8]);
        acc_o[dt] = __builtin_amdgcn_mfma_f32_16x16x32_bf16(pa, vf, acc_o[dt], 0, 0, 0);
      }
    }
    __builtin_amdgcn_s_setprio(0);
    __syncthreads();  // drain (covers next-tile prefetch) after full compute phase
  }
  // full denominator for q=cidx: sum across the 4 rgrp groups
  den += __shfl_xor(den, 16, 64);
  den += __shfl_xor(den, 32, 64);

  const float* qmb = qmask + (size_t)b * LQn + qblk * 64 + w * 16;
  const u16* qres = qbase + (size_t)(w * 16) * En;
  float* obase = out + ((size_t)(b * LQn) + qblk * 64 + w * 16) * En + h * Dn;
#pragma unroll
  for (int r = 0; r < 4; ++r) {
    int qr = rgrp * 4 + r;
    float denq = __shfl(den, qr, 64);  // lane qr holds full den for q=qr
    float fac = qmb[qr] / denq;
#pragma unroll
    for (int dt = 0; dt < 4; ++dt) {
      float v = acc_o[dt][r] * fac + bf2f(qres[(size_t)qr * En + dt * 16 + cidx]);
      obase[(size_t)qr * En + dt * 16 + cidx] = v;
    }
  }
}

extern "C" void kernel_launch(void* const* d_in, const int* in_sizes, int n_in,
                              void* d_out, int out_size, void* d_ws, size_t ws_size,
                              hipStream_t stream) {
  const float* x1 = (const float*)d_in[0];
  const float* x2 = (const float*)d_in[1];
  const float* Wq = (const float*)d_in[2];
  const float* bq = (const float*)d_in[3];
  const float* Wk = (const float*)d_in[4];
  const float* bk = (const float*)d_in[5];
  const float* Wv = (const float*)d_in[6];
  const float* bv = (const float*)d_in[7];
  float* out = (float*)d_out;

  char* ws = (char*)d_ws;
  size_t o = 0;
  u16* x1b = (u16*)(ws + o); o += (size_t)Mtok * En * 2;
  u16* x2b = (u16*)(ws + o); o += (size_t)Mtok * En * 2;
  u16* wqb = (u16*)(ws + o); o += (size_t)En * En * 2;
  u16* wkb = (u16*)(ws + o); o += (size_t)En * En * 2;
  u16* wvb = (u16*)(ws + o); o += (size_t)En * En * 2;
  u16* qbq = (u16*)(ws + o); o += (size_t)Mtok * En * 2;
  u16* kbk = (u16*)(ws + o); o += (size_t)Mtok * En * 2;
  u16* vtb = (u16*)(ws + o); o += (size_t)Mtok * En * 2;  // [E][Mtok] transposed
  float* kbias = (float*)(ws + o); o += (size_t)Mtok * 4;
  float* qmask = (float*)(ws + o); o += (size_t)Mtok * 4;

  // prep: 4096 mask/cvt blocks + 768 weight-cvt blocks
  prep_kernel<<<4864, 256, 0, stream>>>(x1, x2, x1b, x2b, qmask, kbias,
                                        Wq, Wk, Wv, wqb, wkb, wvb);

  dim3 g3(Mtok / 128, En / 128, 3);  // (64, 4, 3) = 768 blocks, 3/CU, 1 round
  gemm3<<<g3, 512, 0, stream>>>(x1b, wqb, bq, qbq, x2b, wkb, bk, kbk, wvb, bv, vtb);

  dim3 ga(Bb * Hn, LQn / 64);  // (64, 16)
  attn_kernel<<<ga, 256, 0, stream>>>(qbq, kbk, vtb, kbias, qmask, out);
}